// Round 4
// baseline (11.676 us; speedup 1.0000x reference)
//
#include <hip/hip_runtime.h>
#include <math.h>

#define NELEM 4  // batch elements per 256-thread block (one per wave)

// Rot(phi, theta, omega) = RZ(omega) RY(theta) RZ(phi), 2x2 complex
__device__ __forceinline__ void make_gate(float phi, float th, float om, float* g) {
  float ct, st, cp, sp, cm, sm;
  __sincosf(0.5f * th, &st, &ct);
  __sincosf(0.5f * (phi + om), &sp, &cp);
  __sincosf(0.5f * (phi - om), &sm, &cm);
  g[0] =  cp * ct; g[1] = -sp * ct;   // g00
  g[2] = -cm * st; g[3] = -sm * st;   // g01
  g[4] =  cm * st; g[5] = -sm * st;   // g10
  g[6] =  cp * ct; g[7] =  sp * ct;   // g11
}

__device__ __forceinline__ float fast_tanh(float x) {
  float e = __expf(2.0f * x);
  return __builtin_fmaf(-2.0f, __builtin_amdgcn_rcpf(e + 1.0f), 1.0f);
}

// Whole 4-qubit 2-layer circuit + <Z0> collapsed to sinusoids in the 4 angles:
//   e = A*t0*t1*t2 + k3r*(Br*k2r + Bi*t0*t1*k2i),  X = P + Q cos a + R sin a
__device__ __forceinline__ float circuit18(float a0, float a1, float a2, float a3,
                                           const float* __restrict__ K) {
  float s0, c0, s1, c1, s2, c2, s3, c3;
  __sincosf(a0, &s0, &c0);
  __sincosf(a1, &s1, &c1);
  __sincosf(a2, &s2, &c2);
  __sincosf(a3, &s3, &c3);
  float t0  = K[0] * c0 + K[1] * s0;
  float t1  = K[2] * c1 + K[3] * s1;
  float t2  = K[4] * c2 + K[5] * s2;
  float k2r = K[6] + K[7] * c2 + K[8] * s2;
  float k2i = K[9] + K[10] * c2 + K[11] * s2;
  float k3r = K[12] + K[13] * c3 + K[14] * s3;
  float tt = t0 * t1;
  return K[15] * (tt * t2) + k3r * (K[16] * k2r + K[17] * (tt * k2i));
}

// stage-1 output index (regroup h=8 ordering) -> source lane (bit permutation)
__device__ __forceinline__ int q1lane(int q) {
  return ((q >> 4) << 4) | (((q >> 1) & 1) << 3) | (((q >> 2) & 3) << 1) | (q & 1);
}

__global__ __launch_bounds__(256, 8) void fused_ttn(
    const float* __restrict__ x, const float* __restrict__ We,
    const float* __restrict__ be, const float* __restrict__ w1,
    const float* __restrict__ w2, const float* __restrict__ w3,
    const float* __restrict__ Wh, const float* __restrict__ bh,
    float* __restrict__ out, int B) {
  __shared__ __align__(16) float sC[3][20];     // 18 consts per stage
  __shared__ __align__(16) float sWe[64];
  __shared__ float sbe[4];
  __shared__ float sWh[10];
  __shared__ float sbh[10];

  const int t = threadIdx.x;
  const int wv = t >> 6, lane = t & 63;
  const int ph = lane >> 3, pw = lane & 7;

  // ---- issue this wave's element loads first (4 x float4 per thread)
  float4 xv[4];
  const float4* xb = (const float4*)x;
  size_t gb = (size_t)blockIdx.x * NELEM + wv;
  if (gb >= (size_t)B) gb = 0;
#pragma unroll
  for (int p1 = 0; p1 < 4; ++p1)
    xv[p1] = xb[gb * 256 + (ph * 4 + p1) * 8 + pw];

  // ---- per-block constant setup (overlaps with loads in flight)
  if (t < 12) {
    int s = t >> 2, w = t & 3;
    const float* W = (s == 0) ? w1 : (s == 1) ? w2 : w3;
    float g[8];
    make_gate(W[w * 3], W[w * 3 + 1], W[w * 3 + 2], g);
    float* K = &sC[s][0];
    float Qt = g[0] * g[0] + g[1] * g[1] - g[4] * g[4] - g[5] * g[5];
    float Rt = (g[0] * g[3] - g[1] * g[2]) - (g[4] * g[7] - g[5] * g[6]);
    if (w < 2) {
      K[w * 2] = Qt; K[w * 2 + 1] = Rt;
    } else if (w == 2) {
      K[4] = Qt; K[5] = Rt;
      float u  = g[0] * g[4] + g[1] * g[5], v  = g[2] * g[6] + g[3] * g[7];
      float p  = g[0] * g[5] - g[1] * g[4], q  = g[2] * g[7] - g[3] * g[6];
      float r1 = g[2] * g[4] + g[3] * g[5], m1 = g[2] * g[5] - g[3] * g[4];
      float r2 = g[0] * g[6] + g[1] * g[7], m2 = g[0] * g[7] - g[1] * g[6];
      K[6] = 0.5f * (u + v);  K[7]  = 0.5f * (u - v);  K[8]  = 0.5f * (m2 - m1);
      K[9] = 0.5f * (p + q);  K[10] = 0.5f * (p - q);  K[11] = 0.5f * (r1 - r2);
    } else {  // w == 3: k3r consts
      float u  = g[0] * g[4] + g[1] * g[5], v  = g[2] * g[6] + g[3] * g[7];
      float m1 = g[2] * g[5] - g[3] * g[4], m2 = g[0] * g[7] - g[1] * g[6];
      K[12] = 0.5f * (u + v); K[13] = 0.5f * (u - v); K[14] = 0.5f * (m2 - m1);
    }
  } else if (t < 15) {
    int s = t - 12;
    const float* W = (s == 0) ? w1 : (s == 1) ? w2 : w3;
    float g[8];
    make_gate(W[18], W[19], W[20], g);  // layer 1, wire 2
    float A    = g[0] * g[0] + g[1] * g[1] - g[4] * g[4] - g[5] * g[5];
    float M01r = g[0] * g[2] + g[1] * g[3] - (g[4] * g[6] + g[5] * g[7]);
    float M01i = (g[0] * g[3] - g[1] * g[2]) - (g[4] * g[7] - g[5] * g[6]);
    sC[s][15] = A; sC[s][16] = 4.0f * M01r; sC[s][17] = -4.0f * M01i;
  }
  if (t < 64) sWe[t] = We[t];
  if (t < 4)  sbe[t] = be[t];
  if (t < 10) { sWh[t] = Wh[t]; sbh[t] = bh[t]; }
  __syncthreads();   // the ONLY barrier — waves run free after this

  // ---- stage 1: one circuit per lane (lane = patch)
  float a0 = sbe[0], a1 = sbe[1], a2 = sbe[2], a3 = sbe[3];
#pragma unroll
  for (int p1 = 0; p1 < 4; ++p1) {
    float4 v = xv[p1];
    float vv[4] = {v.x, v.y, v.z, v.w};
#pragma unroll
    for (int p2 = 0; p2 < 4; ++p2) {
      int f = p1 * 4 + p2;
      a0 = __builtin_fmaf(vv[p2], sWe[f * 4 + 0], a0);
      a1 = __builtin_fmaf(vv[p2], sWe[f * 4 + 1], a1);
      a2 = __builtin_fmaf(vv[p2], sWe[f * 4 + 2], a2);
      a3 = __builtin_fmaf(vv[p2], sWe[f * 4 + 3], a3);
    }
  }
  float e1 = circuit18(fast_tanh(a0), fast_tanh(a1), fast_tanh(a2),
                       fast_tanh(a3), &sC[0][0]);
  // lane holds e1 for stage-1 output index q1 = grp*4+sub (bit-permuted lane)

  // ---- stage 2: all lanes compute circuit c = lane&15 (redundant x4)
  {
    int c = lane & 15;
    int base = ((c >> 3) << 5) | ((c & 7) << 1);
    float b0 = __shfl(e1, q1lane(base), 64);
    float b1 = __shfl(e1, q1lane(base + 1), 64);
    float b2 = __shfl(e1, q1lane(base + 16), 64);
    float b3 = __shfl(e1, q1lane(base + 17), 64);
    e1 = circuit18(b0, b1, b2, b3, &sC[1][0]);  // reuse reg: e2 in e1
  }

  // ---- stage 3: all lanes compute circuit d = lane&3 (redundant x16)
  {
    int d = lane & 3;
    float b0 = __shfl(e1, d * 2, 64);
    float b1 = __shfl(e1, d * 2 + 1, 64);
    float b2 = __shfl(e1, d * 2 + 8, 64);
    float b3 = __shfl(e1, d * 2 + 9, 64);
    e1 = circuit18(b0, b1, b2, b3, &sC[2][0]);  // e3 in e1
  }

  // ---- head: lanes 0..39 write out[b, g3, k]
  if (lane < 40) {
    int g3 = lane / 10;
    int k  = lane - g3 * 10;
    float ev = __shfl(e1, g3, 64);
    size_t b = (size_t)blockIdx.x * NELEM + wv;
    if (b < (size_t)B) out[b * 40 + lane] = ev * sWh[k] + sbh[k];
  }
}

extern "C" void kernel_launch(void* const* d_in, const int* in_sizes, int n_in,
                              void* d_out, int out_size, void* d_ws, size_t ws_size,
                              hipStream_t stream) {
  (void)n_in; (void)out_size; (void)d_ws; (void)ws_size;
  const float* x  = (const float*)d_in[0];
  const float* We = (const float*)d_in[1];
  const float* be = (const float*)d_in[2];
  const float* w1 = (const float*)d_in[3];
  const float* w2 = (const float*)d_in[4];
  const float* w3 = (const float*)d_in[5];
  const float* Wh = (const float*)d_in[6];
  const float* bh = (const float*)d_in[7];
  float* out = (float*)d_out;

  int B = in_sizes[0] / 1024;  // x is (B, 1, 32, 32)
  int blocks = (B + NELEM - 1) / NELEM;
  hipLaunchKernelGGL(fused_ttn, dim3(blocks), dim3(256), 0, stream,
                     x, We, be, w1, w2, w3, Wh, bh, out, B);
}